// Round 3
// baseline (34693.591 us; speedup 1.0000x reference)
//
#include <hip/hip_runtime.h>
#include <stdint.h>

// BiGRU scan, H=1024. Round 3: barrier-free pair-fused dataflow scan.
//  - Unit j owns the PAIR (yf[j], yb[j-1]) (unit 0: (yf[0], yf[1024]); unit
//    1024: yb[1023] alone) and publishes the pre-summed x[j] = yf[j]+yb[j-1]
//    as ONE tagged 8B slot -> 1025 slots/step (was 2050), no consumer add.
//  - Consumers poll exactly the 16 slots their wreg lanes need (4l+256i+m)
//    directly into registers: no LDS, no __syncthreads on the critical path.
//  - Dummy slot 1024 (published by unit 1024, polled by everyone) keeps
//    non-publishing waves inside the 2-parity window (deadlock safety).
//  - q-chain on its own 129 blocks (2 units/wave; 8x slack) so the p-chain
//    critical path is pure. 257 p-blocks + 129 q-blocks = 386 <= 512
//    co-resident at __launch_bounds__(256,2).

#define H   1024
#define HH  1025
#define N3  3075      // 3*HH
#define TQ  512
#define TP  4096
#define MTOT 4608     // TQ + TP rows in gh (q tokens first, then p tokens)
#define GH_ELEMS ((size_t)MTOT * (size_t)N3)
#define PBLK 257      // p-chain blocks
#define QBLK 129      // q-chain blocks
#define CSTRIDE 1040  // slots per (chain,parity): 1024 x + dummy + pad

typedef unsigned long long ull;

__device__ __forceinline__ float sigm(float x) { return 1.f / (1.f + __expf(-x)); }
__device__ __forceinline__ float fast_tanh(float x) {
    float e = __expf(2.f * x);
    return (e - 1.f) / (e + 1.f);
}
__device__ __forceinline__ ull aload(const ull* p) {
    return __hip_atomic_load((ull*)p, __ATOMIC_RELAXED, __HIP_MEMORY_SCOPE_AGENT);
}
__device__ __forceinline__ void astore(ull* p, ull v) {
    __hip_atomic_store(p, v, __ATOMIC_RELAXED, __HIP_MEMORY_SCOPE_AGENT);
}

// ---------------------------------------------------------------------------
// gh GEMM (unchanged from round 2): gh[dir][m][r] = h0[m][dir] . Whh_dir[r] + bhh
// ---------------------------------------------------------------------------
__global__ __launch_bounds__(256, 2) void gh_gemm(
    const float* __restrict__ eq, const float* __restrict__ ep,
    const float* __restrict__ fs, const float* __restrict__ fe,
    const float* __restrict__ Whh_f, const float* __restrict__ bhh_f,
    const float* __restrict__ Whh_b, const float* __restrict__ bhh_b,
    float* __restrict__ ghf, float* __restrict__ ghb)
{
    const int dir = blockIdx.z;
    const float* W  = dir ? Whh_b : Whh_f;
    const float* bh = dir ? bhh_b : bhh_f;
    float* gh = dir ? ghb : ghf;
    const int n0 = blockIdx.x * 128;
    const int m0 = blockIdx.y * 128;

    __shared__ float As[16][132];
    __shared__ float Bs[16][132];

    float acc[8][8];
#pragma unroll
    for (int i = 0; i < 8; i++)
#pragma unroll
        for (int j = 0; j < 8; j++) acc[i][j] = 0.f;

    const int tid = threadIdx.x;
    const int tx = tid & 15, ty = tid >> 4;

    for (int k0 = 0; k0 < HH; k0 += 16) {
#pragma unroll
        for (int u = 0; u < 8; u++) {
            int lin = tid + 256 * u;
            int k = lin & 15;
            int m = lin >> 4;
            int gm = m0 + m;
            int gk = k0 + k;
            float v = 0.f;
            if (gk < HH) {
                bool isq = gm < TQ;
                const float* e = isq ? eq : ep;
                int t = isq ? gm : gm - TQ;
                if (dir == 0)            v = e[(size_t)t * 2048 + gk];
                else if (gk < 1023)      v = e[(size_t)t * 2048 + 1025 + gk];
                else if (!isq)           v = (gk == 1023) ? fs[t] : fe[t];
            }
            As[k][m] = v;
        }
#pragma unroll
        for (int u = 0; u < 8; u++) {
            int lin = tid + 256 * u;
            int k = lin & 15;
            int r = lin >> 4;
            int gr = n0 + r, gk = k0 + k;
            Bs[k][r] = (gr < N3 && gk < HH) ? W[(size_t)gr * HH + gk] : 0.f;
        }
        __syncthreads();
#pragma unroll
        for (int kk = 0; kk < 16; kk++) {
            float4 a0 = *(const float4*)&As[kk][ty * 4];
            float4 a1 = *(const float4*)&As[kk][64 + ty * 4];
            float4 b0 = *(const float4*)&Bs[kk][tx * 4];
            float4 b1 = *(const float4*)&Bs[kk][64 + tx * 4];
            float a[8] = {a0.x, a0.y, a0.z, a0.w, a1.x, a1.y, a1.z, a1.w};
            float b[8] = {b0.x, b0.y, b0.z, b0.w, b1.x, b1.y, b1.z, b1.w};
#pragma unroll
            for (int i = 0; i < 8; i++)
#pragma unroll
                for (int j = 0; j < 8; j++) acc[i][j] += a[i] * b[j];
        }
        __syncthreads();
    }
#pragma unroll
    for (int i = 0; i < 8; i++) {
        int gm = m0 + ((i < 4) ? (ty * 4 + i) : (64 + ty * 4 + i - 4));
#pragma unroll
        for (int j = 0; j < 8; j++) {
            int gr = n0 + ((j < 4) ? (tx * 4 + j) : (64 + tx * 4 + j - 4));
            if (gr < N3) gh[(size_t)gm * N3 + gr] = acc[i][j] + bh[gr];
        }
    }
}

// ---------------------------------------------------------------------------
// Pair-fused scan body. One wave handles NU units; unit u owns:
//   elem A: u<=1023 -> (dir0,row u) ; u==1024 -> (dir1,row 1023)
//   elem B: u==0 -> (dir0,row 1024) ; 1<=u<=1023 -> (dir1,row u-1) ; else none
// Publishes slot u (u<=1023: x[u]=yA+yB ; u==1024: dummy=yA).
// ---------------------------------------------------------------------------
template <int NU>
__device__ __forceinline__ void scan_impl(
    int ubase, int lane, int nT,
    const float* __restrict__ emb,   // eq or ep
    const float* __restrict__ fs,    // null for q-chain
    const float* __restrict__ Wih_f, const float* __restrict__ bih_f,
    const float* __restrict__ Wih_b, const float* __restrict__ bih_b,
    const float* __restrict__ ghF,   // gh dir0, pre-offset to this chain's token 0
    const float* __restrict__ ghB,   // gh dir1, pre-offset
    ull* __restrict__ cm,            // this chain's comm base: [2][CSTRIDE]
    float* __restrict__ outc)        // this chain's out base
{
    const int NE = 2 * NU;
    const int NR = 3 * NE;
    ubase = __builtin_amdgcn_readfirstlane(ubase);

    int  dir_[NE], row_[NE], h0col_[NE], h0mode_[NE];
    bool val_[NE], st_[NE];
#pragma unroll
    for (int k = 0; k < NU; k++) {
        int u = ubase + k;
        // elem A = 2k
        if (u <= 1023)      { dir_[2*k]=0; row_[2*k]=u;    val_[2*k]=true;  st_[2*k]=true; }
        else if (u == 1024) { dir_[2*k]=1; row_[2*k]=1023; val_[2*k]=true;  st_[2*k]=true; }
        else                { dir_[2*k]=0; row_[2*k]=0;    val_[2*k]=false; st_[2*k]=false; }
        // elem B = 2k+1
        if (u == 0)         { dir_[2*k+1]=0; row_[2*k+1]=1024; val_[2*k+1]=true;  st_[2*k+1]=false; }
        else if (u <= 1023) { dir_[2*k+1]=1; row_[2*k+1]=u-1;  val_[2*k+1]=true;  st_[2*k+1]=true; }
        else                { dir_[2*k+1]=0; row_[2*k+1]=0;    val_[2*k+1]=false; st_[2*k+1]=false; }
    }
#pragma unroll
    for (int e = 0; e < NE; e++) {
        dir_[e] = __builtin_amdgcn_readfirstlane(dir_[e]);
        row_[e] = __builtin_amdgcn_readfirstlane(row_[e]);
        if (dir_[e] == 0) { h0col_[e] = row_[e]; h0mode_[e] = 0; }
        else if (row_[e] < 1023) { h0col_[e] = 1025 + row_[e]; h0mode_[e] = 0; }
        else { h0col_[e] = 0; h0mode_[e] = 1; }   // dir1,row1023 -> fs[t] (or 0)
    }

    // register-resident Wih rows (k-split: lane l holds k = 4l + 256i + m)
    float wreg[NR][16];
    float breg[NR];
    const float* ghp_[NE];
#pragma unroll
    for (int e = 0; e < NE; e++) {
        const float* W  = dir_[e] ? Wih_b : Wih_f;
        const float* bb = dir_[e] ? bih_b : bih_f;
        ghp_[e] = (dir_[e] ? ghB : ghF) + row_[e];
#pragma unroll
        for (int g = 0; g < 3; g++) {
            const float* wr = W + (size_t)(g * HH + row_[e]) * H;
#pragma unroll
            for (int i = 0; i < 4; i++) {
                float4 w4 = *(const float4*)(wr + i * 256 + lane * 4);
                wreg[e*3+g][i*4+0] = w4.x; wreg[e*3+g][i*4+1] = w4.y;
                wreg[e*3+g][i*4+2] = w4.z; wreg[e*3+g][i*4+3] = w4.w;
            }
            breg[e*3+g] = bb[g * HH + row_[e]];
        }
    }

    // gh/h0 pipeline (scalar loads; lgkmcnt path, never blocks the polls)
    float ghc[NR], h0c[NE];
    auto ldgh = [&](int tt, float gh[], float h0[]) {
        size_t base = (size_t)tt * N3;
#pragma unroll
        for (int e = 0; e < NE; e++) {
#pragma unroll
            for (int g = 0; g < 3; g++)
                gh[e*3+g] = ghp_[e][base + g * HH];
            h0[e] = (h0mode_[e] == 0) ? emb[(size_t)tt * 2048 + h0col_[e]]
                                      : (fs ? fs[tt] : 0.f);
        }
    };
    ldgh(0, ghc, h0c);

    for (int t = 0; t < nT; ++t) {
        ull v[17];
        float x[16];
        ull* wrs = cm + (t & 1) * CSTRIDE;
        const ull* rd = cm + ((t + 1) & 1) * CSTRIDE;

        if (t) {
#pragma unroll
            for (int i = 0; i < 4; i++)
#pragma unroll
                for (int m = 0; m < 4; m++)
                    v[i*4+m] = aload(&rd[4*lane + 256*i + m]);
            v[16] = aload(&rd[1024]);
        }

        // prefetch next step's gh/h0 (scalar; overlaps the spin below)
        float ghn[NR], h0n[NE];
        const bool more = (t + 1) < nT;
        if (more) ldgh(t + 1, ghn, h0n);

        if (t) {
            const unsigned tag = (unsigned)t;
            for (;;) {
                bool ok = true;
#pragma unroll
                for (int u2 = 0; u2 < 17; u2++) {
                    if ((unsigned)(v[u2] >> 32) != tag) {
                        ok = false;
                        int slot = (u2 < 16) ? (4*lane + 256*(u2 >> 2) + (u2 & 3)) : 1024;
                        v[u2] = aload(&rd[slot]);
                    }
                }
                if (ok) break;
            }
#pragma unroll
            for (int u2 = 0; u2 < 16; u2++) x[u2] = __uint_as_float((unsigned)v[u2]);
        } else {
#pragma unroll
            for (int u2 = 0; u2 < 16; u2++) x[u2] = 0.f;
        }

        // dots + butterfly reduce
        float acc[NR];
#pragma unroll
        for (int r = 0; r < NR; r++) {
            float s = 0.f;
#pragma unroll
            for (int i = 0; i < 16; i++) s += wreg[r][i] * x[i];
            acc[r] = s;
        }
#pragma unroll
        for (int off = 32; off > 0; off >>= 1)
#pragma unroll
            for (int r = 0; r < NR; r++) acc[r] += __shfl_xor(acc[r], off, 64);

        // gates (all lanes, redundantly)
        float y[NE];
#pragma unroll
        for (int e = 0; e < NE; e++) {
            float rr = sigm(acc[e*3+0] + breg[e*3+0] + ghc[e*3+0]);
            float zz = sigm(acc[e*3+1] + breg[e*3+1] + ghc[e*3+1]);
            float nn = fast_tanh(acc[e*3+2] + breg[e*3+2] + rr * ghc[e*3+2]);
            y[e] = (1.f - zz) * nn + zz * h0c[e];
        }

        // publish pre-summed x slots first, then out stores
        if (lane == 0) {
            const ull tagout = ((ull)(unsigned)(t + 1)) << 32;
#pragma unroll
            for (int k = 0; k < NU; k++) {
                int u = ubase + k;
                if (u <= 1024) {
                    float xv = y[2*k] + ((u <= 1023) ? y[2*k+1] : 0.f);
                    astore(&wrs[u], tagout | (ull)__float_as_uint(xv));
                }
            }
#pragma unroll
            for (int e = 0; e < NE; e++) {
                if (val_[e] && st_[e]) {
                    int col = dir_[e] ? (1024 + row_[e]) : row_[e];
                    outc[(size_t)t * 2048 + col] = y[e];
                }
            }
        }

        if (more) {
#pragma unroll
            for (int r = 0; r < NR; r++) ghc[r] = ghn[r];
#pragma unroll
            for (int e = 0; e < NE; e++) h0c[e] = h0n[e];
        }
    }
}

__global__ __launch_bounds__(256, 2) void bigru_scan(
    const float* __restrict__ eq, const float* __restrict__ ep,
    const float* __restrict__ fs,
    const float* __restrict__ Wih_f, const float* __restrict__ bih_f,
    const float* __restrict__ Wih_b, const float* __restrict__ bih_b,
    const float* __restrict__ ghf, const float* __restrict__ ghb,
    ull* __restrict__ comm, float* __restrict__ out)
{
    const int wave = threadIdx.x >> 6;
    const int lane = threadIdx.x & 63;
    if ((int)blockIdx.x < PBLK) {
        int ub = blockIdx.x * 4 + wave;            // 1 unit per wave
        if (ub > 1024) return;
        scan_impl<1>(ub, lane, TP, ep, fs,
                     Wih_f, bih_f, Wih_b, bih_b,
                     ghf + (size_t)TQ * N3, ghb + (size_t)TQ * N3,
                     comm, out + (size_t)TQ * 2048);
    } else {
        int qi = (blockIdx.x - PBLK) * 4 + wave;   // 2 units per wave
        int ub = 2 * qi;
        if (ub > 1024) return;
        scan_impl<2>(ub, lane, TQ, eq, nullptr,
                     Wih_f, bih_f, Wih_b, bih_b,
                     ghf, ghb,
                     comm + 2 * CSTRIDE, out);
    }
}

extern "C" void kernel_launch(void* const* d_in, const int* in_sizes, int n_in,
                              void* d_out, int out_size, void* d_ws, size_t ws_size,
                              hipStream_t stream) {
    const float* eq    = (const float*)d_in[0];
    const float* ep    = (const float*)d_in[1];
    const float* fs    = (const float*)d_in[2];
    const float* fe    = (const float*)d_in[3];
    const float* Wih_f = (const float*)d_in[4];
    const float* Whh_f = (const float*)d_in[5];
    const float* bih_f = (const float*)d_in[6];
    const float* bhh_f = (const float*)d_in[7];
    const float* Wih_b = (const float*)d_in[8];
    const float* Whh_b = (const float*)d_in[9];
    const float* bih_b = (const float*)d_in[10];
    const float* bhh_b = (const float*)d_in[11];
    float* out = (float*)d_out;

    float* ghf = (float*)d_ws;
    float* ghb = ghf + GH_ELEMS;
    size_t commOff = ((2 * GH_ELEMS * sizeof(float)) + 4095) & ~(size_t)4095;
    ull* comm = (ull*)((char*)d_ws + commOff);

    hipMemsetAsync(comm, 0, (size_t)4 * CSTRIDE * sizeof(ull), stream);

    dim3 ggrid((N3 + 127) / 128, MTOT / 128, 2);
    gh_gemm<<<ggrid, 256, 0, stream>>>(eq, ep, fs, fe, Whh_f, bhh_f, Whh_b, bhh_b, ghf, ghb);

    bigru_scan<<<dim3(PBLK + QBLK), dim3(256), 0, stream>>>(
        eq, ep, fs, Wih_f, bih_f, Wih_b, bih_b, ghf, ghb, comm, out);
}

// Round 4
// 16476.660 us; speedup vs baseline: 2.1056x; 2.1056x over previous
//
#include <hip/hip_runtime.h>
#include <stdint.h>

// BiGRU scan, H=1024. Round 4: block-gathered pair-fused dataflow scan.
//  - 1024 pre-summed x slots (pairs (yf[j], yb[j-1]); unit 0 = (yf[0], yf[1024])).
//    Store-only leftover elem yb[1023] rides block127/wave3. No dummy slot.
//  - 128 blocks x 256 thr; wave owns 2 units (4 elems; 12 Wih rows in regs,
//    SHARED between p and q chains). q-chain folded into same blocks (t<512).
//  - Gather at BLOCK granularity: each thread polls 2 (p) [+2 q] 16B granules
//    via batched global_load_dwordx4 sc0 sc1 asm (1 waitcnt per retry round),
//    writes LDS; per-wave release flags replace __syncthreads (no vmcnt drain).
//  - Publish: one 16B sc0sc1 store per wave per chain (2 tagged slots).

#define H    1024
#define HH   1025
#define N3   3075
#define TQ   512
#define TP   4096
#define MTOT 4608
#define GH_ELEMS ((size_t)MTOT * (size_t)N3)
#define NBLK 128

typedef unsigned long long ull;
typedef unsigned int u32x4 __attribute__((ext_vector_type(4)));

__device__ __forceinline__ float sigm(float x) { return 1.f / (1.f + __expf(-x)); }
__device__ __forceinline__ float fast_tanh(float x) {
    float e = __expf(2.f * x);
    return (e - 1.f) / (e + 1.f);
}

__device__ __forceinline__ void load2g(const ull* p0, const ull* p1, u32x4& a, u32x4& b) {
    asm volatile(
        "global_load_dwordx4 %0, %2, off sc0 sc1\n\t"
        "global_load_dwordx4 %1, %3, off sc0 sc1\n\t"
        "s_waitcnt vmcnt(0)"
        : "=&v"(a), "=&v"(b) : "v"(p0), "v"(p1) : "memory");
}
__device__ __forceinline__ void load4g(const ull* p0, const ull* p1, const ull* p2, const ull* p3,
                                       u32x4& a, u32x4& b, u32x4& c, u32x4& d) {
    asm volatile(
        "global_load_dwordx4 %0, %4, off sc0 sc1\n\t"
        "global_load_dwordx4 %1, %5, off sc0 sc1\n\t"
        "global_load_dwordx4 %2, %6, off sc0 sc1\n\t"
        "global_load_dwordx4 %3, %7, off sc0 sc1\n\t"
        "s_waitcnt vmcnt(0)"
        : "=&v"(a), "=&v"(b), "=&v"(c), "=&v"(d)
        : "v"(p0), "v"(p1), "v"(p2), "v"(p3) : "memory");
}
__device__ __forceinline__ void store1g(ull* p, u32x4 v) {
    asm volatile("global_store_dwordx4 %0, %1, off sc0 sc1" :: "v"(p), "v"(v) : "memory");
}
__device__ __forceinline__ bool freshg(const u32x4& v, unsigned tag) {
    return v[1] == tag && v[3] == tag;
}

// ---------------------------------------------------------------------------
// gh GEMM (unchanged): gh[dir][m][r] = h0[m][dir] . Whh_dir[r] + bhh_dir[r]
// ---------------------------------------------------------------------------
__global__ __launch_bounds__(256, 2) void gh_gemm(
    const float* __restrict__ eq, const float* __restrict__ ep,
    const float* __restrict__ fs, const float* __restrict__ fe,
    const float* __restrict__ Whh_f, const float* __restrict__ bhh_f,
    const float* __restrict__ Whh_b, const float* __restrict__ bhh_b,
    float* __restrict__ ghf, float* __restrict__ ghb)
{
    const int dir = blockIdx.z;
    const float* W  = dir ? Whh_b : Whh_f;
    const float* bh = dir ? bhh_b : bhh_f;
    float* gh = dir ? ghb : ghf;
    const int n0 = blockIdx.x * 128;
    const int m0 = blockIdx.y * 128;

    __shared__ float As[16][132];
    __shared__ float Bs[16][132];

    float acc[8][8];
#pragma unroll
    for (int i = 0; i < 8; i++)
#pragma unroll
        for (int j = 0; j < 8; j++) acc[i][j] = 0.f;

    const int tid = threadIdx.x;
    const int tx = tid & 15, ty = tid >> 4;

    for (int k0 = 0; k0 < HH; k0 += 16) {
#pragma unroll
        for (int u = 0; u < 8; u++) {
            int lin = tid + 256 * u;
            int k = lin & 15;
            int m = lin >> 4;
            int gm = m0 + m;
            int gk = k0 + k;
            float v = 0.f;
            if (gk < HH) {
                bool isq = gm < TQ;
                const float* e = isq ? eq : ep;
                int t = isq ? gm : gm - TQ;
                if (dir == 0)            v = e[(size_t)t * 2048 + gk];
                else if (gk < 1023)      v = e[(size_t)t * 2048 + 1025 + gk];
                else if (!isq)           v = (gk == 1023) ? fs[t] : fe[t];
            }
            As[k][m] = v;
        }
#pragma unroll
        for (int u = 0; u < 8; u++) {
            int lin = tid + 256 * u;
            int k = lin & 15;
            int r = lin >> 4;
            int gr = n0 + r, gk = k0 + k;
            Bs[k][r] = (gr < N3 && gk < HH) ? W[(size_t)gr * HH + gk] : 0.f;
        }
        __syncthreads();
#pragma unroll
        for (int kk = 0; kk < 16; kk++) {
            float4 a0 = *(const float4*)&As[kk][ty * 4];
            float4 a1 = *(const float4*)&As[kk][64 + ty * 4];
            float4 b0 = *(const float4*)&Bs[kk][tx * 4];
            float4 b1 = *(const float4*)&Bs[kk][64 + tx * 4];
            float a[8] = {a0.x, a0.y, a0.z, a0.w, a1.x, a1.y, a1.z, a1.w};
            float b[8] = {b0.x, b0.y, b0.z, b0.w, b1.x, b1.y, b1.z, b1.w};
#pragma unroll
            for (int i = 0; i < 8; i++)
#pragma unroll
                for (int j = 0; j < 8; j++) acc[i][j] += a[i] * b[j];
        }
        __syncthreads();
    }
#pragma unroll
    for (int i = 0; i < 8; i++) {
        int gm = m0 + ((i < 4) ? (ty * 4 + i) : (64 + ty * 4 + i - 4));
#pragma unroll
        for (int j = 0; j < 8; j++) {
            int gr = n0 + ((j < 4) ? (tx * 4 + j) : (64 + tx * 4 + j - 4));
            if (gr < N3) gh[(size_t)gm * N3 + gr] = acc[i][j] + bh[gr];
        }
    }
}

// ---------------------------------------------------------------------------
// Persistent scan.
// ---------------------------------------------------------------------------
__global__ __launch_bounds__(256, 1) void bigru_scan(
    const float* __restrict__ eq, const float* __restrict__ ep,
    const float* __restrict__ fs,
    const float* __restrict__ Wih_f, const float* __restrict__ bih_f,
    const float* __restrict__ Wih_b, const float* __restrict__ bih_b,
    const float* __restrict__ ghf,   // ghb contiguous at ghf + GH_ELEMS
    ull* __restrict__ comm,          // [chain p|q][parity][1024] tagged x slots
    float* __restrict__ out)         // h_q (512*2048) then h_p (4096*2048)
{
    __shared__ float xsh[2][2][1024];   // [parity][chain p=0,q=1][j]
    __shared__ unsigned xflag[4];

    const int tid  = threadIdx.x;
    const int wave = tid >> 6;
    const int lane = tid & 63;
    const int u0   = __builtin_amdgcn_readfirstlane((int)blockIdx.x * 8 + wave * 2);
    const bool extra = (u0 == 1022);    // this wave also owns elem (dir1,row1023)

    if (tid < 4) xflag[tid] = 0;
    __syncthreads();

    // elems: e0=A(u0)=(0,u0); e1=B(u0)= u0? (1,u0-1):(0,1024); e2=A(u0+1); e3=B(u0+1)=(1,u0)
    int dirE[4], rowE[4];
    bool stE[4];
    dirE[0] = 0; rowE[0] = u0;     stE[0] = true;
    if (u0 == 0) { dirE[1] = 0; rowE[1] = 1024;   stE[1] = false; }
    else         { dirE[1] = 1; rowE[1] = u0 - 1; stE[1] = true;  }
    dirE[2] = 0; rowE[2] = u0 + 1; stE[2] = true;
    dirE[3] = 1; rowE[3] = u0;     stE[3] = true;

    // register-resident Wih rows (k-split: lane l holds k = 4l + 256i + m)
    float wreg[12][16], breg[12];
#pragma unroll
    for (int e = 0; e < 4; e++) {
        const float* W  = dirE[e] ? Wih_b : Wih_f;
        const float* bb = dirE[e] ? bih_b : bih_f;
#pragma unroll
        for (int g = 0; g < 3; g++) {
            const float* wr = W + (size_t)(g * HH + rowE[e]) * H;
#pragma unroll
            for (int i = 0; i < 4; i++) {
                float4 w4 = *(const float4*)(wr + i * 256 + lane * 4);
                wreg[e*3+g][i*4+0] = w4.x; wreg[e*3+g][i*4+1] = w4.y;
                wreg[e*3+g][i*4+2] = w4.z; wreg[e*3+g][i*4+3] = w4.w;
            }
            breg[e*3+g] = bb[g * HH + rowE[e]];
        }
    }
    float wregX[3][16], bregX[3];
    if (extra) {
#pragma unroll
        for (int g = 0; g < 3; g++) {
            const float* wr = Wih_b + (size_t)(g * HH + 1023) * H;
#pragma unroll
            for (int i = 0; i < 4; i++) {
                float4 w4 = *(const float4*)(wr + i * 256 + lane * 4);
                wregX[g][i*4+0] = w4.x; wregX[g][i*4+1] = w4.y;
                wregX[g][i*4+2] = w4.z; wregX[g][i*4+3] = w4.w;
            }
            bregX[g] = bih_b[g * HH + 1023];
        }
    }

    // scalar gh/h0 offsets (wave-uniform)
    size_t ghoff[4];
    int h0col[4], h0m[4];
#pragma unroll
    for (int e = 0; e < 4; e++) {
        ghoff[e] = (dirE[e] ? GH_ELEMS : (size_t)0) + (size_t)rowE[e];
        if (dirE[e] == 0)            { h0col[e] = rowE[e];        h0m[e] = 0; }
        else if (rowE[e] <= 1022)    { h0col[e] = 1025 + rowE[e]; h0m[e] = 0; }
        else                         { h0col[e] = 0;              h0m[e] = 1; }
    }
    const size_t ghoffX = GH_ELEMS + 1023;

    auto ldgh = [&](int tokgh, int tok, const float* emb, const float* fsp,
                    float gh[12], float h0[4], float ghX[3], float& h0X) {
        size_t tb = (size_t)tokgh * N3;
#pragma unroll
        for (int e = 0; e < 4; e++) {
#pragma unroll
            for (int g = 0; g < 3; g++)
                gh[e*3+g] = ghf[ghoff[e] + tb + (size_t)g * HH];
            h0[e] = (h0m[e] == 0) ? emb[(size_t)tok * 2048 + h0col[e]]
                                  : (fsp ? fsp[tok] : 0.f);
        }
        if (extra) {
#pragma unroll
            for (int g = 0; g < 3; g++) ghX[g] = ghf[ghoffX + tb + (size_t)g * HH];
            h0X = fsp ? fsp[tok] : 0.f;
        }
    };

    // compute one chain's step: dots from xsh -> gates -> publish + out
    auto chain_step = [&](int c, const float gh[12], const float h0[4],
                          const float ghX[3], float h0X,
                          ull* cmc, float* outb, int t) {
        float acc[12], accX[3];
        if (t) {
            float x[16];
#pragma unroll
            for (int i = 0; i < 4; i++) {
                float4 xv = *(const float4*)&xsh[t & 1][c][i * 256 + 4 * lane];
                x[i*4+0] = xv.x; x[i*4+1] = xv.y; x[i*4+2] = xv.z; x[i*4+3] = xv.w;
            }
#pragma unroll
            for (int r = 0; r < 12; r++) {
                float s = 0.f;
#pragma unroll
                for (int i = 0; i < 16; i++) s += wreg[r][i] * x[i];
                acc[r] = s;
            }
            if (extra) {
#pragma unroll
                for (int g = 0; g < 3; g++) {
                    float s = 0.f;
#pragma unroll
                    for (int i = 0; i < 16; i++) s += wregX[g][i] * x[i];
                    accX[g] = s;
                }
            }
#pragma unroll
            for (int off = 32; off > 0; off >>= 1) {
#pragma unroll
                for (int r = 0; r < 12; r++) acc[r] += __shfl_xor(acc[r], off, 64);
                if (extra) {
#pragma unroll
                    for (int g = 0; g < 3; g++) accX[g] += __shfl_xor(accX[g], off, 64);
                }
            }
        } else {
#pragma unroll
            for (int r = 0; r < 12; r++) acc[r] = 0.f;
            accX[0] = accX[1] = accX[2] = 0.f;
        }

        float y[4];
#pragma unroll
        for (int e = 0; e < 4; e++) {
            float rr = sigm(acc[e*3+0] + breg[e*3+0] + gh[e*3+0]);
            float zz = sigm(acc[e*3+1] + breg[e*3+1] + gh[e*3+1]);
            float nn = fast_tanh(acc[e*3+2] + breg[e*3+2] + rr * gh[e*3+2]);
            y[e] = (1.f - zz) * nn + zz * h0[e];
        }

        if (lane == 0) {
            u32x4 pk;
            pk[0] = __float_as_uint(y[0] + y[1]); pk[1] = (unsigned)(t + 1);
            pk[2] = __float_as_uint(y[2] + y[3]); pk[3] = (unsigned)(t + 1);
            store1g(cmc + (size_t)(t & 1) * 1024 + u0, pk);

            size_t ob = (size_t)t * 2048;
            outb[ob + u0]     = y[0];
            outb[ob + u0 + 1] = y[2];
            if (stE[1]) outb[ob + 1023 + u0] = y[1];
            outb[ob + 1024 + u0] = y[3];
            if (extra) {
                float rr = sigm(accX[0] + bregX[0] + ghX[0]);
                float zz = sigm(accX[1] + bregX[1] + ghX[1]);
                float nn = fast_tanh(accX[2] + bregX[2] + rr * ghX[2]);
                outb[ob + 2047] = (1.f - zz) * nn + zz * h0X;
            }
        }
    };

    // gh/h0 pipeline
    float ghcP[12], h0cP[4], ghcXP[3]; float h0XP = 0.f;
    float ghcQ[12], h0cQ[4], ghcXQ[3]; float h0XQ = 0.f;
    ldgh(TQ, 0, ep, fs, ghcP, h0cP, ghcXP, h0XP);
    ldgh(0, 0, eq, nullptr, ghcQ, h0cQ, ghcXQ, h0XQ);

    ull* cmP = comm;
    ull* cmQ = comm + 2 * 1024;
    float* outP = out + (size_t)TQ * 2048;
    float* outQ = out;

    for (int t = 0; t < TP; t++) {
        const bool doq = (t < TQ);

        // prefetch next step's gh/h0 (scalar s_loads; overlap gather+compute)
        float ghnP[12], h0nP[4], ghnXP[3]; float h0nXP = 0.f;
        float ghnQ[12], h0nQ[4], ghnXQ[3]; float h0nXQ = 0.f;
        const bool mp = (t + 1) < TP;
        const bool mq = (t + 1) < TQ;
        if (mp) ldgh(TQ + t + 1, t + 1, ep, fs, ghnP, h0nP, ghnXP, h0nXP);
        if (mq) ldgh(t + 1, t + 1, eq, nullptr, ghnQ, h0nQ, ghnXQ, h0nXQ);

        if (t) {
            const int rpar = (t + 1) & 1;           // parity holding tag t
            const unsigned tag = (unsigned)t;
            const ull* pp0 = cmP + (size_t)rpar * 1024 + 2 * tid;
            const ull* pp1 = pp0 + 512;
            const ull* qq0 = cmQ + (size_t)rpar * 1024 + 2 * tid;
            const ull* qq1 = qq0 + 512;

            u32x4 a0, a1, a2, a3;
            if (doq) load4g(pp0, pp1, qq0, qq1, a0, a1, a2, a3);
            else     load2g(pp0, pp1, a0, a1);
            for (;;) {
                bool ok = freshg(a0, tag) && freshg(a1, tag);
                if (doq) ok = ok && freshg(a2, tag) && freshg(a3, tag);
                if (ok) break;
                if (doq) load4g(pp0, pp1, qq0, qq1, a0, a1, a2, a3);
                else     load2g(pp0, pp1, a0, a1);
            }

            const int par = t & 1;
            xsh[par][0][2 * tid]             = __uint_as_float(a0[0]);
            xsh[par][0][2 * tid + 1]         = __uint_as_float(a0[2]);
            xsh[par][0][2 * (tid + 256)]     = __uint_as_float(a1[0]);
            xsh[par][0][2 * (tid + 256) + 1] = __uint_as_float(a1[2]);
            if (doq) {
                xsh[par][1][2 * tid]             = __uint_as_float(a2[0]);
                xsh[par][1][2 * tid + 1]         = __uint_as_float(a2[2]);
                xsh[par][1][2 * (tid + 256)]     = __uint_as_float(a3[0]);
                xsh[par][1][2 * (tid + 256) + 1] = __uint_as_float(a3[2]);
            }
            __threadfence_block();
            if (lane == 0) *(volatile unsigned*)&xflag[wave] = (unsigned)t;
            for (;;) {
                bool ok = true;
#pragma unroll
                for (int w = 0; w < 4; w++) {
                    unsigned f = *(volatile unsigned*)&xflag[w];
                    ok &= ((int)(f - (unsigned)t) >= 0);
                }
                if (ok) break;
            }
            __threadfence_block();
        }

        chain_step(0, ghcP, h0cP, ghcXP, h0XP, cmP, outP, t);
        if (doq) chain_step(1, ghcQ, h0cQ, ghcXQ, h0XQ, cmQ, outQ, t);

        if (mp) {
#pragma unroll
            for (int r = 0; r < 12; r++) ghcP[r] = ghnP[r];
#pragma unroll
            for (int e = 0; e < 4; e++) h0cP[e] = h0nP[e];
#pragma unroll
            for (int g = 0; g < 3; g++) ghcXP[g] = ghnXP[g];
            h0XP = h0nXP;
        }
        if (mq) {
#pragma unroll
            for (int r = 0; r < 12; r++) ghcQ[r] = ghnQ[r];
#pragma unroll
            for (int e = 0; e < 4; e++) h0cQ[e] = h0nQ[e];
#pragma unroll
            for (int g = 0; g < 3; g++) ghcXQ[g] = ghnXQ[g];
            h0XQ = h0nXQ;
        }
    }
}

extern "C" void kernel_launch(void* const* d_in, const int* in_sizes, int n_in,
                              void* d_out, int out_size, void* d_ws, size_t ws_size,
                              hipStream_t stream) {
    const float* eq    = (const float*)d_in[0];
    const float* ep    = (const float*)d_in[1];
    const float* fs    = (const float*)d_in[2];
    const float* fe    = (const float*)d_in[3];
    const float* Wih_f = (const float*)d_in[4];
    const float* Whh_f = (const float*)d_in[5];
    const float* bih_f = (const float*)d_in[6];
    const float* bhh_f = (const float*)d_in[7];
    const float* Wih_b = (const float*)d_in[8];
    const float* Whh_b = (const float*)d_in[9];
    const float* bih_b = (const float*)d_in[10];
    const float* bhh_b = (const float*)d_in[11];
    float* out = (float*)d_out;

    float* ghf = (float*)d_ws;
    float* ghb = ghf + GH_ELEMS;
    size_t commOff = ((2 * GH_ELEMS * sizeof(float)) + 4095) & ~(size_t)4095;
    ull* comm = (ull*)((char*)d_ws + commOff);

    // 2 chains x 2 parities x 1024 tagged slots
    hipMemsetAsync(comm, 0, (size_t)4 * 1024 * sizeof(ull), stream);

    dim3 ggrid((N3 + 127) / 128, MTOT / 128, 2);
    gh_gemm<<<ggrid, 256, 0, stream>>>(eq, ep, fs, fe, Whh_f, bhh_f, Whh_b, bhh_b, ghf, ghb);

    bigru_scan<<<dim3(NBLK), dim3(256), 0, stream>>>(
        eq, ep, fs, Wih_f, bih_f, Wih_b, bih_b, ghf, comm, out);
}